// Round 6
// baseline (35210.077 us; speedup 1.0000x reference)
//
#include <hip/hip_runtime.h>
#include <hip/hip_bf16.h>
#include <cstddef>

// Problem constants
constexpr int T = 8192;   // SEQ_LEN
constexpr int H = 1024;   // NHID == NIN
constexpr int N3 = 3 * H; // 3072
constexpr int G = 64;     // scan blocks (cooperative), 512 threads each
constexpr int UPB = 16;   // hidden units per block (G*UPB == H)
constexpr int NW = 512;   // h words per slot (2 fp32 per u64)
constexpr unsigned long long SENT = ~0ull;  // impossible bit pattern (|h|<1)

// ---------------------------------------------------------------------------
// Kernel 1: x_proj = xs @ w_ih.T + b   (M=8192, N=3072, K=1024, fp32)
// ---------------------------------------------------------------------------
#define BM 64
#define BN 64
#define BK 16
#define PAD 20

__global__ __launch_bounds__(256) void xproj_gemm(const float* __restrict__ A,   // xs [M,K]
                                                  const float* __restrict__ W,   // w_ih [N,K]
                                                  const float* __restrict__ bias,
                                                  float* __restrict__ C) {      // [M,N]
  __shared__ float As[BM * PAD];
  __shared__ float Bs[BN * PAD];
  const int tid = threadIdx.x;
  const int tx = tid & 15;   // N dir
  const int ty = tid >> 4;   // M dir
  const int m0 = blockIdx.y * BM;
  const int n0 = blockIdx.x * BN;

  const int lr = tid >> 2;        // 0..63 row to load
  const int lc = (tid & 3) * 4;   // col offset (float4)

  float acc[4][4] = {};

  for (int k0 = 0; k0 < H; k0 += BK) {
    float4 av = *(const float4*)&A[(size_t)(m0 + lr) * H + k0 + lc];
    float4 bv = *(const float4*)&W[(size_t)(n0 + lr) * H + k0 + lc];
    *(float4*)&As[lr * PAD + lc] = av;
    *(float4*)&Bs[lr * PAD + lc] = bv;
    __syncthreads();
#pragma unroll
    for (int kk = 0; kk < BK; kk += 4) {
      float4 a[4], b[4];
#pragma unroll
      for (int i = 0; i < 4; ++i) a[i] = *(const float4*)&As[(ty * 4 + i) * PAD + kk];
#pragma unroll
      for (int j = 0; j < 4; ++j) b[j] = *(const float4*)&Bs[(tx * 4 + j) * PAD + kk];
#pragma unroll
      for (int i = 0; i < 4; ++i)
#pragma unroll
        for (int j = 0; j < 4; ++j)
          acc[i][j] += a[i].x * b[j].x + a[i].y * b[j].y + a[i].z * b[j].z + a[i].w * b[j].w;
    }
    __syncthreads();
  }

  float4 bb = *(const float4*)&bias[n0 + tx * 4];
#pragma unroll
  for (int i = 0; i < 4; ++i) {
    float4 o;
    o.x = acc[i][0] + bb.x;
    o.y = acc[i][1] + bb.y;
    o.z = acc[i][2] + bb.z;
    o.w = acc[i][3] + bb.w;
    *(float4*)&C[(size_t)(m0 + ty * 4 + i) * N3 + n0 + tx * 4] = o;
  }
}

// ---------------------------------------------------------------------------
// Kernel 2: persistent GRU scan — sentinel dataflow exchange (tag-free).
//
// Exchange buffer: 3 rotating slots x 512 u64 words; word w_idx = u/2 packs
// {h[2u], h[2u+1]} (both fp32). |h|<1 always, so 0xFFFF..F is unreachable ->
// sentinel marks "not yet written". Physical address permutation
// p = (w_idx&7)*64 + (w_idx>>3) spreads each block's 8 words across 8 cache
// lines (kills same-line store serialization). Per step per block:
//   wave0: 8 u64 loads/lane (512 total, HALF of the tagged scheme), batch
//   re-poll on sentinel, unpack into XOR-swizzled LDS; __syncthreads;
//   each wave: reset its own word in slot (t+2)%3 (safe: gather of h_t done
//   => all readers of h_{t-1} done), FMA + butterfly + gates;
//   s_waitcnt vmcnt(0) (reset globally visible first), ONE u64 store of the
//   wave's 2 new h values into slot (t+1)%3; out[] stores after.
// ---------------------------------------------------------------------------
__device__ __forceinline__ float sigmoidf_fast(float x) {
  return 1.0f / (1.0f + __expf(-x));
}
__device__ __forceinline__ float tanhf_fast(float x) {
  float ax = fabsf(x);
  float e = __expf(-2.0f * ax);      // e <= 1, always stable
  float t = (1.0f - e) / (1.0f + e);
  return copysignf(t, x);
}

__global__ __launch_bounds__(512, 1) void gru_scan(const float* __restrict__ xp,
                                                   const float* __restrict__ whh,
                                                   const float* __restrict__ bn,
                                                   unsigned long long* __restrict__ vbuf, // 3*NW words
                                                   float* __restrict__ out) {  // 2*T*H floats
  __shared__ float lds_h[H];  // XOR-swizzled broadcast buffer: addr = u ^ (u>>6)

  const int tid = threadIdx.x;
  const int w = tid >> 6;    // wave 0..7
  const int l = tid & 63;
  const int b = blockIdx.x;
  const int ublk = b * UPB + 2 * w;  // first of this wave's 2 units
  const int pword = w * 64 + b;      // permuted slot index of this wave's word

  // Load w_hh into registers. Row r6: gate g = r6>>1, unit = ublk + (r6&1).
  // Lane l holds elements k = j*64 + l.
  float wreg[6][16];
#pragma unroll
  for (int r6 = 0; r6 < 6; ++r6) {
    const int g = r6 >> 1;
    const int u = ublk + (r6 & 1);
    const float* wrow = whh + (size_t)(g * H + u) * H;
#pragma unroll
    for (int j = 0; j < 16; ++j) wreg[r6][j] = wrow[j * 64 + l];
  }

  const int myu = ublk + (l & 1);                 // meaningful for l < 2
  const float bnv = (l < 2) ? bn[myu] : 0.0f;
  const bool gate_lane = (l < 2);

#pragma unroll 1
  for (int t = 0; t < T; ++t) {
    unsigned long long* vb = vbuf + (size_t)(t % 3) * NW;        // h_t
    unsigned long long* vn = vbuf + (size_t)((t + 1) % 3) * NW;  // h_{t+1}
    unsigned long long* vr = vbuf + (size_t)((t + 2) % 3) * NW;  // to reset

    // Early-issue per-unit xp inputs; latency hides under the poll.
    float ir = 0.f, iz = 0.f, ig = 0.f;
    if (gate_lane) {
      const float* xpt = xp + (size_t)t * N3;
      ir = xpt[myu];
      iz = xpt[H + myu];
      ig = xpt[2 * H + myu];
    }

    if (w == 0) {
      // Wave 0: gather all 512 words (8/lane), batch re-poll on sentinel.
      unsigned long long pv[8];
#pragma unroll
      for (int k = 0; k < 8; ++k)
        pv[k] = __hip_atomic_load(vb + k * 64 + l, __ATOMIC_RELAXED,
                                  __HIP_MEMORY_SCOPE_AGENT);
      while (true) {
        unsigned stale = 0;
#pragma unroll
        for (int k = 0; k < 8; ++k)
          if (pv[k] == SENT) stale |= (1u << k);
        if (!__any(stale != 0)) break;
#pragma unroll
        for (int k = 0; k < 8; ++k)
          if (stale & (1u << k))
            pv[k] = __hip_atomic_load(vb + k * 64 + l, __ATOMIC_RELAXED,
                                      __HIP_MEMORY_SCOPE_AGENT);
      }
      // Unpack: phys p = k*64+l -> word w_idx = l*8+k -> units u=l*16+2k, u+1.
#pragma unroll
      for (int k = 0; k < 8; ++k) {
        const int u = l * 16 + 2 * k;
        const int xr = u >> 6;  // same for u and u+1 (u even)
        lds_h[(u) ^ xr] = __uint_as_float((unsigned)pv[k]);
        lds_h[(u + 1) ^ xr] = __uint_as_float((unsigned)(pv[k] >> 32));
      }
    }
    __syncthreads();  // releases fresh lds_h to all waves

    // Reset this wave's word in the slot that will hold h_{t+3}. Safe now:
    // gather of h_t complete => all readers of h_{t-1} are done.
    if (l == 0)
      __hip_atomic_store(vr + pword, SENT, __ATOMIC_RELAXED,
                         __HIP_MEMORY_SCOPE_AGENT);

    // All waves: gather h from LDS (XOR layout; 2-way alias, conflict-free).
    float hv[16];
#pragma unroll
    for (int j = 0; j < 16; ++j) hv[j] = lds_h[(j * 64 + l) ^ j];

    float acc[6] = {0.f, 0.f, 0.f, 0.f, 0.f, 0.f};
#pragma unroll
    for (int j = 0; j < 16; ++j) {
#pragma unroll
      for (int r6 = 0; r6 < 6; ++r6) acc[r6] += wreg[r6][j] * hv[j];
    }

    // Butterfly reduction over 64 lanes; every lane ends with all 6 sums.
#pragma unroll
    for (int off = 32; off >= 1; off >>= 1) {
#pragma unroll
      for (int r6 = 0; r6 < 6; ++r6) acc[r6] += __shfl_xor(acc[r6], off, 64);
    }

    // Gates (all lanes compute; only lanes 0/1 have meaningful inputs).
    const float hold = gate_lane ? lds_h[myu ^ (myu >> 6)] : 0.0f;
    const int li = l & 1;
    float r = sigmoidf_fast(ir + acc[li]);
    float z = sigmoidf_fast(iz + acc[2 + li]);
    float gg = tanhf_fast(ig + r * (acc[4 + li] + bnv));
    float hnew = (1.0f - z) * gg + z * hold;

    // Pack the wave's 2 values into one u64; lane 0 stores it.
    const float h0 = __shfl(hnew, 0, 64);
    const float h1 = __shfl(hnew, 1, 64);
    // Ensure the reset store (and everything prior) is globally visible
    // before the new h word becomes visible (atomics bypass L2: ack==visible).
    asm volatile("s_waitcnt vmcnt(0)" ::: "memory");
    if (l == 0) {
      unsigned long long word =
          ((unsigned long long)__float_as_uint(h1) << 32) |
          (unsigned long long)__float_as_uint(h0);
      __hip_atomic_store(vn + pword, word, __ATOMIC_RELAXED,
                         __HIP_MEMORY_SCOPE_AGENT);
    }

    // Output writes (fire-and-forget, after the critical store).
    if (gate_lane) {
      out[(size_t)t * H + myu] = hnew;
      out[(size_t)T * H + (size_t)t * H + myu] = hnew;  // second tuple copy
    }
  }
}

// ---------------------------------------------------------------------------
extern "C" void kernel_launch(void* const* d_in, const int* in_sizes, int n_in,
                              void* d_out, int out_size, void* d_ws, size_t ws_size,
                              hipStream_t stream) {
  const float* xs   = (const float*)d_in[0];
  const float* w_ih = (const float*)d_in[1];
  const float* w_hh = (const float*)d_in[2];
  const float* b    = (const float*)d_in[3];
  const float* bn   = (const float*)d_in[4];
  float* out = (float*)d_out;

  // Workspace layout: x_proj (T*3H fp32 = 96MB) | vbuf (3*NW u64)
  float* xp = (float*)d_ws;
  unsigned long long* vbuf = (unsigned long long*)(xp + (size_t)T * N3);

  // Slot 0 = h_0 = 0.0 packed (0x0 != sentinel); slots 1,2 = sentinel.
  hipMemsetAsync(vbuf, 0, NW * sizeof(unsigned long long), stream);
  hipMemsetAsync(vbuf + NW, 0xFF, 2 * NW * sizeof(unsigned long long), stream);

  dim3 ggrid(N3 / BN, T / BM);
  xproj_gemm<<<ggrid, 256, 0, stream>>>(xs, w_ih, b, xp);

  void* args[] = {(void*)&xp, (void*)&w_hh, (void*)&bn, (void*)&vbuf, (void*)&out};
  hipLaunchCooperativeKernel((void*)gru_scan, dim3(G), dim3(512), args, 0, stream);
}

// Round 7
// 27172.690 us; speedup vs baseline: 1.2958x; 1.2958x over previous
//
#include <hip/hip_runtime.h>
#include <hip/hip_bf16.h>
#include <cstddef>

// Problem constants
constexpr int T = 8192;   // SEQ_LEN
constexpr int H = 1024;   // NHID == NIN
constexpr int N3 = 3 * H; // 3072
constexpr int G = 64;     // scan blocks (cooperative)
constexpr int UPB = 16;   // hidden units per block (G*UPB == H)

// ---------------------------------------------------------------------------
// Kernel 1: x_proj = xs @ w_ih.T + b   (M=8192, N=3072, K=1024, fp32)
// ---------------------------------------------------------------------------
#define BM 64
#define BN 64
#define BK 16
#define PAD 20

__global__ __launch_bounds__(256) void xproj_gemm(const float* __restrict__ A,   // xs [M,K]
                                                  const float* __restrict__ W,   // w_ih [N,K]
                                                  const float* __restrict__ bias,
                                                  float* __restrict__ C) {      // [M,N]
  __shared__ float As[BM * PAD];
  __shared__ float Bs[BN * PAD];
  const int tid = threadIdx.x;
  const int tx = tid & 15;   // N dir
  const int ty = tid >> 4;   // M dir
  const int m0 = blockIdx.y * BM;
  const int n0 = blockIdx.x * BN;

  const int lr = tid >> 2;        // 0..63 row to load
  const int lc = (tid & 3) * 4;   // col offset (float4)

  float acc[4][4] = {};

  for (int k0 = 0; k0 < H; k0 += BK) {
    float4 av = *(const float4*)&A[(size_t)(m0 + lr) * H + k0 + lc];
    float4 bv = *(const float4*)&W[(size_t)(n0 + lr) * H + k0 + lc];
    *(float4*)&As[lr * PAD + lc] = av;
    *(float4*)&Bs[lr * PAD + lc] = bv;
    __syncthreads();
#pragma unroll
    for (int kk = 0; kk < BK; kk += 4) {
      float4 a[4], b[4];
#pragma unroll
      for (int i = 0; i < 4; ++i) a[i] = *(const float4*)&As[(ty * 4 + i) * PAD + kk];
#pragma unroll
      for (int j = 0; j < 4; ++j) b[j] = *(const float4*)&Bs[(tx * 4 + j) * PAD + kk];
#pragma unroll
      for (int i = 0; i < 4; ++i)
#pragma unroll
        for (int j = 0; j < 4; ++j)
          acc[i][j] += a[i].x * b[j].x + a[i].y * b[j].y + a[i].z * b[j].z + a[i].w * b[j].w;
    }
    __syncthreads();
  }

  float4 bb = *(const float4*)&bias[n0 + tx * 4];
#pragma unroll
  for (int i = 0; i < 4; ++i) {
    float4 o;
    o.x = acc[i][0] + bb.x;
    o.y = acc[i][1] + bb.y;
    o.z = acc[i][2] + bb.z;
    o.w = acc[i][3] + bb.w;
    *(float4*)&C[(size_t)(m0 + ty * 4 + i) * N3 + n0 + tx * 4] = o;
  }
}

// ---------------------------------------------------------------------------
// Kernel 2: persistent GRU scan — dedicated-poller dataflow pipeline.
//
// Exchange format (proven in R4): h element = u64 {hi: tag, lo: fp32}; h_t
// carries tag=t; one relaxed agent-scope 8B atomic store per element; two
// rotating global slots; memset gives tag0 = h_0 = 0. Slot overwrite (h_{t+2}
// over h_t) is safe: it happens only after the whole grid consumed h_{t+1}.
//
// NEW (R7): 9 waves/block. Wave 8 = dedicated poller: poll slot t (16 u64
// loads/lane, batch re-poll) -> publish values to lds_h[t&1] -> barrier ->
// immediately poll slot t+1, OVERLAPPING the workers' compute+store of step
// t. Workers (waves 0-7, 2 units each): barrier -> read lds_h[t&1] -> 96
// FMAs -> butterfly -> gates -> tagged store -> out writes -> xp prefetch
// for t+1 (HBM latency hides under the next barrier wait).
//
// LDS double-buffer safety comes from the barrier itself: a worker reaching
// barrier t has finished all reads of lds_h[(t-1)&1], which is exactly the
// buffer the poller writes next (iteration t+1, before barrier t+1).
// ---------------------------------------------------------------------------
__device__ __forceinline__ float sigmoidf_fast(float x) {
  return 1.0f / (1.0f + __expf(-x));
}
__device__ __forceinline__ float tanhf_fast(float x) {
  float ax = fabsf(x);
  float e = __expf(-2.0f * ax);      // e <= 1, always stable
  float t = (1.0f - e) / (1.0f + e);
  return copysignf(t, x);
}

__global__ __launch_bounds__(576, 1) void gru_scan(const float* __restrict__ xp,
                                                   const float* __restrict__ whh,
                                                   const float* __restrict__ bn,
                                                   unsigned long long* __restrict__ hbuf, // 2*H tagged
                                                   float* __restrict__ out) {  // 2*T*H floats
  __shared__ float lds_h[2][H];  // double-buffered broadcast of h_t

  const int tid = threadIdx.x;
  const int w = tid >> 6;    // wave 0..8
  const int l = tid & 63;
  const int b = blockIdx.x;

  if (w == 8) {
    // ---------------- dedicated poller wave ----------------
#pragma unroll 1
    for (int t = 0; t < T; ++t) {
      unsigned long long* hb = hbuf + (size_t)(t & 1) * H;
      unsigned long long pv[16];
#pragma unroll
      for (int j = 0; j < 16; ++j)
        pv[j] = __hip_atomic_load(hb + j * 64 + l, __ATOMIC_RELAXED,
                                  __HIP_MEMORY_SCOPE_AGENT);
      while (true) {
        unsigned stale = 0;
#pragma unroll
        for (int j = 0; j < 16; ++j)
          if ((unsigned)(pv[j] >> 32) < (unsigned)t) stale |= (1u << j);
        if (!__any(stale != 0)) break;
#pragma unroll
        for (int j = 0; j < 16; ++j)
          if (stale & (1u << j))
            pv[j] = __hip_atomic_load(hb + j * 64 + l, __ATOMIC_RELAXED,
                                      __HIP_MEMORY_SCOPE_AGENT);
      }
#pragma unroll
      for (int j = 0; j < 16; ++j)
        lds_h[t & 1][j * 64 + l] = __uint_as_float((unsigned)pv[j]);
      __syncthreads();  // publish lds_h[t&1]; then immediately poll t+1
    }
  } else {
    // ---------------- worker waves (2 units each) ----------------
    const int ublk = b * UPB + 2 * w;

    // w_hh rows in registers. Row r6: gate g = r6>>1, unit = ublk + (r6&1).
    // Lane l holds elements k = j*64 + l.
    float wreg[6][16];
#pragma unroll
    for (int r6 = 0; r6 < 6; ++r6) {
      const int g = r6 >> 1;
      const int u = ublk + (r6 & 1);
      const float* wrow = whh + (size_t)(g * H + u) * H;
#pragma unroll
      for (int j = 0; j < 16; ++j) wreg[r6][j] = wrow[j * 64 + l];
    }

    const int myu = ublk + l;  // meaningful for l < 2
    const bool gate_lane = (l < 2);
    const float bnv = gate_lane ? bn[myu] : 0.0f;

    // Software-pipelined xp loads: values for step t loaded during step t-1.
    float ir = 0.f, iz = 0.f, ig = 0.f;
    if (gate_lane) {
      ir = xp[myu];
      iz = xp[H + myu];
      ig = xp[2 * H + myu];
    }

#pragma unroll 1
    for (int t = 0; t < T; ++t) {
      __syncthreads();  // wait for poller to publish lds_h[t&1]

      float hv[16];
#pragma unroll
      for (int j = 0; j < 16; ++j) hv[j] = lds_h[t & 1][j * 64 + l];

      float acc[6] = {0.f, 0.f, 0.f, 0.f, 0.f, 0.f};
#pragma unroll
      for (int j = 0; j < 16; ++j) {
#pragma unroll
        for (int r6 = 0; r6 < 6; ++r6) acc[r6] += wreg[r6][j] * hv[j];
      }

      // Butterfly reduction over 64 lanes; all lanes get all 6 sums.
#pragma unroll
      for (int off = 32; off >= 1; off >>= 1) {
#pragma unroll
        for (int r6 = 0; r6 < 6; ++r6) acc[r6] += __shfl_xor(acc[r6], off, 64);
      }

      if (gate_lane) {
        const float hold = lds_h[t & 1][myu];
        // lane l handles unit ublk+l: hr=acc[l], hz=acc[2+l], hg=acc[4+l]
        float r = sigmoidf_fast(ir + acc[l]);
        float z = sigmoidf_fast(iz + acc[2 + l]);
        float gg = tanhf_fast(ig + r * (acc[4 + l] + bnv));
        float hnew = (1.0f - z) * gg + z * hold;
        unsigned long long pk =
            ((unsigned long long)(unsigned)(t + 1) << 32) |
            (unsigned long long)__float_as_uint(hnew);
        __hip_atomic_store(hbuf + (size_t)((t + 1) & 1) * H + myu, pk,
                           __ATOMIC_RELAXED, __HIP_MEMORY_SCOPE_AGENT);
        // Output writes (fire-and-forget, after the critical store).
        out[(size_t)t * H + myu] = hnew;
        out[(size_t)T * H + (size_t)t * H + myu] = hnew;

        // Prefetch next step's xp; latency hides under next barrier wait.
        if (t + 1 < T) {
          const float* xpn = xp + (size_t)(t + 1) * N3;
          ir = xpn[myu];
          iz = xpn[H + myu];
          ig = xpn[2 * H + myu];
        }
      }
    }
  }
}

// ---------------------------------------------------------------------------
extern "C" void kernel_launch(void* const* d_in, const int* in_sizes, int n_in,
                              void* d_out, int out_size, void* d_ws, size_t ws_size,
                              hipStream_t stream) {
  const float* xs   = (const float*)d_in[0];
  const float* w_ih = (const float*)d_in[1];
  const float* w_hh = (const float*)d_in[2];
  const float* b    = (const float*)d_in[3];
  const float* bn   = (const float*)d_in[4];
  float* out = (float*)d_out;

  // Workspace layout: x_proj (T*3H fp32 = 96MB) | tagged hbuf (2*H u64)
  float* xp = (float*)d_ws;
  unsigned long long* hbuf = (unsigned long long*)(xp + (size_t)T * N3);

  // h0 = 0 with tag 0 (step-0 poll needs tag >= 0); re-done every call.
  hipMemsetAsync(hbuf, 0, 2 * H * sizeof(unsigned long long), stream);

  dim3 ggrid(N3 / BN, T / BM);
  xproj_gemm<<<ggrid, 256, 0, stream>>>(xs, w_ih, b, xp);

  void* args[] = {(void*)&xp, (void*)&w_hh, (void*)&bn, (void*)&hbuf, (void*)&out};
  hipLaunchCooperativeKernel((void*)gru_scan, dim3(G), dim3(576), args, 0, stream);
}